// Round 1
// baseline (107.115 us; speedup 1.0000x reference)
//
#include <hip/hip_runtime.h>
#include <math.h>

// ChamferLoss: set1/set2 [8, 4096, 3] fp32 -> scalar
// out = (mean_i min_j dist(s1_i, s2_j) + mean_j min_i dist) / 4096
//     = (sum of all 65536 per-point min distances) / (8*4096*4096)

#define BATCH 8
#define NPTS  4096
#define QB    256            // queries per block
#define THREADS 512
#define HALF_PTS (NPTS/2)    // 2048 DB points per half-group

__global__ __launch_bounds__(THREADS, 2)
void chamfer_main(const float* __restrict__ set1,
                  const float* __restrict__ set2,
                  float* __restrict__ out)
{
    __shared__ float db[NPTS * 3];     // 48 KB: one full DB batch, xyzxyz...
    __shared__ float redA[QB];         // half-combine scratch
    __shared__ float redB[THREADS / 64];

    const int blk = blockIdx.x;        // 0..255
    const int dir = blk >> 7;          // 0: set1->set2, 1: set2->set1
    const int rem = blk & 127;
    const int b   = rem >> 4;          // batch 0..7
    const int qb  = rem & 15;          // query block 0..15

    const float* __restrict__ Q  = dir ? set2 : set1;
    const float* __restrict__ DB = dir ? set1 : set2;

    // --- stage DB batch into LDS (coalesced float4) ---
    const float4* g4 = (const float4*)(DB + (size_t)b * NPTS * 3);  // 3072 float4
    float4* l4 = (float4*)db;
    #pragma unroll
    for (int i = 0; i < 6; ++i)
        l4[threadIdx.x + i * THREADS] = g4[threadIdx.x + i * THREADS];

    // --- load this thread's query point ---
    const int qlocal = threadIdx.x & (QB - 1);
    const int half   = threadIdx.x >> 8;          // 0 or 1
    const int q      = qb * QB + qlocal;
    const float* qp  = Q + ((size_t)b * NPTS + q) * 3;
    const float qx = qp[0], qy = qp[1], qz = qp[2];

    __syncthreads();

    // --- scan this half's 2048 DB points, min of squared distance ---
    const float4* s4 = (const float4*)db + half * (HALF_PTS * 3 / 4); // +1536
    float dmin = 3.4e38f;

    #pragma unroll 4
    for (int c = 0; c < HALF_PTS / 4; ++c) {
        const float4 p0 = s4[c * 3 + 0];
        const float4 p1 = s4[c * 3 + 1];
        const float4 p2 = s4[c * 3 + 2];
        float dx, dy, dz, d2;
        // point 4c+0 = (p0.x, p0.y, p0.z)
        dx = qx - p0.x; dy = qy - p0.y; dz = qz - p0.z;
        d2 = dx * dx + dy * dy + dz * dz; dmin = fminf(dmin, d2);
        // point 4c+1 = (p0.w, p1.x, p1.y)
        dx = qx - p0.w; dy = qy - p1.x; dz = qz - p1.y;
        d2 = dx * dx + dy * dy + dz * dz; dmin = fminf(dmin, d2);
        // point 4c+2 = (p1.z, p1.w, p2.x)
        dx = qx - p1.z; dy = qy - p1.w; dz = qz - p2.x;
        d2 = dx * dx + dy * dy + dz * dz; dmin = fminf(dmin, d2);
        // point 4c+3 = (p2.y, p2.z, p2.w)
        dx = qx - p2.y; dy = qy - p2.z; dz = qz - p2.w;
        d2 = dx * dx + dy * dy + dz * dz; dmin = fminf(dmin, d2);
    }

    // --- combine the two halves per query ---
    if (half) redA[qlocal] = dmin;
    __syncthreads();

    float dist = 0.0f;
    if (!half) dist = sqrtf(fminf(dmin, redA[qlocal]));
    // upper-half threads contribute 0 to the sum

    // --- wave reduce (64 lanes) ---
    #pragma unroll
    for (int off = 32; off > 0; off >>= 1)
        dist += __shfl_down(dist, off);
    if ((threadIdx.x & 63) == 0) redB[threadIdx.x >> 6] = dist;
    __syncthreads();

    if (threadIdx.x == 0) {
        float s = 0.0f;
        #pragma unroll
        for (int w = 0; w < THREADS / 64; ++w) s += redB[w];
        // scale: / (BATCH * NPTS) for the means, then / NPTS
        atomicAdd(out, s * (1.0f / (float)((size_t)BATCH * NPTS * NPTS)));
    }
}

extern "C" void kernel_launch(void* const* d_in, const int* in_sizes, int n_in,
                              void* d_out, int out_size, void* d_ws, size_t ws_size,
                              hipStream_t stream) {
    const float* s1 = (const float*)d_in[0];
    const float* s2 = (const float*)d_in[1];
    float* out = (float*)d_out;

    hipMemsetAsync(out, 0, sizeof(float), stream);  // d_out is poisoned 0xAA each call
    chamfer_main<<<dim3(256), dim3(THREADS), 0, stream>>>(s1, s2, out);
}

// Round 2
// 82.863 us; speedup vs baseline: 1.2927x; 1.2927x over previous
//
#include <hip/hip_runtime.h>
#include <math.h>
#include <float.h>

// ChamferLoss: set1/set2 [8, 4096, 3] fp32 -> scalar
// out = sum over both directions of per-point min distances / (8*4096*4096)
//
// Inner loop uses d^2 = ||q||^2 + (||p||^2 - 2 q.p); ||p||^2 staged in LDS as
// the .w of a float4 per point, ||q||^2 added after the min (query-constant).
// 4 VALU insts per (query, point) pair: 3 fma + 1 min.

#define BATCH   8
#define NPTS    4096
#define THREADS 512
#define QB      128          // queries per block
#define QPT     4            // queries per thread
#define NGRP    16           // scan groups (THREADS*QPT/QB)
#define PPG     (NPTS/NGRP)  // 256 points scanned per group

__global__ __launch_bounds__(THREADS, 4)
void chamfer_main(const float* __restrict__ set1,
                  const float* __restrict__ set2,
                  float* __restrict__ out)
{
    __shared__ float4 dbp[NPTS];          // 64 KB: {x,y,z,||p||^2} per point
    __shared__ float  part[NGRP][QB];     // 8 KB: per-group partial mins

    const int blk = blockIdx.x;           // 0..511
    const int dir = blk >> 8;             // 0: set1->set2, 1: set2->set1
    const int rem = blk & 255;
    const int b   = rem >> 5;             // batch 0..7
    const int qb  = rem & 31;             // query block 0..31

    const float* __restrict__ Q  = dir ? set2 : set1;
    const float* __restrict__ DB = dir ? set1 : set2;
    const float* __restrict__ DBb = DB + (size_t)b * NPTS * 3;

    const int t = threadIdx.x;

    // --- stage DB batch into LDS with precomputed ||p||^2 ---
    for (int i = t; i < NPTS; i += THREADS) {
        const float x = DBb[3 * i + 0];
        const float y = DBb[3 * i + 1];
        const float z = DBb[3 * i + 2];
        dbp[i] = make_float4(x, y, z, fmaf(x, x, fmaf(y, y, z * z)));
    }

    // --- this thread's 4 query coefficient sets (-2*q) ---
    const int l = t & 31;                 // lane-in-group
    const int g = t >> 5;                 // scan group 0..15
    const int qbase = qb * QB;

    float qa[QPT], qbc[QPT], qc[QPT], dmin[QPT];
    #pragma unroll
    for (int j = 0; j < QPT; ++j) {
        const float* qp = Q + ((size_t)b * NPTS + qbase + l + 32 * j) * 3;
        qa[j]  = -2.0f * qp[0];
        qbc[j] = -2.0f * qp[1];
        qc[j]  = -2.0f * qp[2];
        dmin[j] = FLT_MAX;
    }

    __syncthreads();

    // --- scan this group's 256 points for 4 queries ---
    const float4* __restrict__ s4 = dbp + g * PPG;

    #pragma unroll 2
    for (int c = 0; c < PPG / 4; ++c) {
        const float4 P0 = s4[c * 4 + 0];
        const float4 P1 = s4[c * 4 + 1];
        const float4 P2 = s4[c * 4 + 2];
        const float4 P3 = s4[c * 4 + 3];
        #pragma unroll
        for (int j = 0; j < QPT; ++j) {
            const float a = qa[j], bb = qbc[j], cc = qc[j];
            float d0 = fmaf(a, P0.x, fmaf(bb, P0.y, fmaf(cc, P0.z, P0.w)));
            float d1 = fmaf(a, P1.x, fmaf(bb, P1.y, fmaf(cc, P1.z, P1.w)));
            float d2 = fmaf(a, P2.x, fmaf(bb, P2.y, fmaf(cc, P2.z, P2.w)));
            float d3 = fmaf(a, P3.x, fmaf(bb, P3.y, fmaf(cc, P3.z, P3.w)));
            dmin[j] = fminf(dmin[j], fminf(fminf(d0, d1), fminf(d2, d3)));
        }
    }

    // --- write per-group partial mins ---
    #pragma unroll
    for (int j = 0; j < QPT; ++j)
        part[g][l + 32 * j] = dmin[j];
    __syncthreads();

    // --- combine groups, finish d = sqrt(max(q^2 + m, 0)), reduce sum ---
    float dist = 0.0f;
    if (t < QB) {
        float m = part[0][t];
        #pragma unroll
        for (int gg = 1; gg < NGRP; ++gg)
            m = fminf(m, part[gg][t]);
        const float* qp = Q + ((size_t)b * NPTS + qbase + t) * 3;
        const float qx = qp[0], qy = qp[1], qz = qp[2];
        const float q2 = fmaf(qx, qx, fmaf(qy, qy, qz * qz));
        dist = sqrtf(fmaxf(q2 + m, 0.0f));
    }

    // wave reduce (only waves 0,1 have nonzero), one atomic per wave
    #pragma unroll
    for (int off = 32; off > 0; off >>= 1)
        dist += __shfl_down(dist, off);
    if (t < QB && (t & 63) == 0)
        atomicAdd(out, dist * (1.0f / (float)((size_t)BATCH * NPTS * NPTS)));
}

extern "C" void kernel_launch(void* const* d_in, const int* in_sizes, int n_in,
                              void* d_out, int out_size, void* d_ws, size_t ws_size,
                              hipStream_t stream) {
    const float* s1 = (const float*)d_in[0];
    const float* s2 = (const float*)d_in[1];
    float* out = (float*)d_out;

    hipMemsetAsync(out, 0, sizeof(float), stream);  // d_out poisoned 0xAA each call
    chamfer_main<<<dim3(512), dim3(THREADS), 0, stream>>>(s1, s2, out);
}